// Round 6
// baseline (98.112 us; speedup 1.0000x reference)
//
#include <hip/hip_runtime.h>
#include <hip/hip_bf16.h>
#include <math.h>

#define D     128
#define NT    256            // B*T
#define HD    32
#define LD    32
#define NCH   2              // n's per score block
#define NC    (NT/NCH)       // 128 chunks
#define NROWS (NT*D)         // 32768

static __device__ inline unsigned short f2bf(float f) {
    __hip_bfloat16 b = __float2bfloat16(f);
    return *reinterpret_cast<unsigned short*>(&b);
}

// ---------------------------------------------------------------------------
// K1: pa[row][h] = b1[h] + z[row]·W1a[h,:],  pb[row][h] = z[row]·W1b[h,:]
//     ca2[row] = sum_h (w2[h]/2)*pa[row][h], cb2[row] likewise for pb.
// W1 lives in VGPRs (lane h owns its rows); z staged in LDS, read as
// 2-address broadcast b128 (no per-element LDS cost). 128 rows/block.
// ---------------------------------------------------------------------------
__global__ __launch_bounds__(512) void pab_kernel(
    const float* __restrict__ z, const float* __restrict__ W1,
    const float* __restrict__ b1, const float* __restrict__ W2,
    float* __restrict__ pa, float* __restrict__ pb,
    float* __restrict__ ca2, float* __restrict__ cb2)
{
    __shared__ float sz[128][LD];        // 16 KB, linear
    const int t    = threadIdx.x;
    const int row0 = blockIdx.x * 128;

    {   // stage z: 1024 float4, coalesced
        const float4* zsrc = (const float4*)(z + (size_t)row0 * LD);
        float4* zdst = (float4*)&sz[0][0];
        zdst[t]       = zsrc[t];
        zdst[t + 512] = zsrc[t + 512];
    }

    const int h    = t & 31;
    const int slot = t >> 5;             // 0..15
    float wa[LD], wb[LD];                // this thread's W1 rows in VGPRs
    #pragma unroll
    for (int k = 0; k < 8; ++k) {
        *(float4*)&wa[k * 4] = *(const float4*)&W1[h * 64 + k * 4];
        *(float4*)&wb[k * 4] = *(const float4*)&W1[h * 64 + 32 + k * 4];
    }
    const float bias = b1[h];
    const float w2h  = 0.5f * W2[h];
    __syncthreads();

    #pragma unroll 2
    for (int q = 0; q < 8; ++q) {
        const int r = slot + 16 * q;     // 2 distinct r per wave -> broadcast reads
        float aA = bias, aB = 0.f;
        #pragma unroll
        for (int k = 0; k < 8; ++k) {
            float4 v = *(const float4*)&sz[r][k * 4];
            aA = fmaf(v.x, wa[k*4+0], aA); aA = fmaf(v.y, wa[k*4+1], aA);
            aA = fmaf(v.z, wa[k*4+2], aA); aA = fmaf(v.w, wa[k*4+3], aA);
            aB = fmaf(v.x, wb[k*4+0], aB); aB = fmaf(v.y, wb[k*4+1], aB);
            aB = fmaf(v.z, wb[k*4+2], aB); aB = fmaf(v.w, wb[k*4+3], aB);
        }
        const int row = row0 + r;
        pa[row * HD + h] = aA;
        pb[row * HD + h] = aB;
        float vA = w2h * aA, vB = w2h * aB;
        #pragma unroll
        for (int m = 16; m >= 1; m >>= 1) {
            vA += __shfl_xor(vA, m, 32);
            vB += __shfl_xor(vB, m, 32);
        }
        if (h == 0) { ca2[row] = vA; cb2[row] = vB; }
    }
}

// ---------------------------------------------------------------------------
// K2 (hot): Spart[nc][i][j] = sum_{n in chunk} [ ca2[n,i] + cb2[n,j]
//                              + sum_h (w2[h]/2)*|pa[n,i,h]+pb[n,j,h]| ]
// lane = i (pa row from small LDS tile); pb rows read DIRECTLY from global
// with wave-uniform addresses (scalarizes; zero LDS traffic for pb).
// 64x64 tile x 2 n's; grid 512 = 2 blocks/CU.
// ---------------------------------------------------------------------------
__global__ __launch_bounds__(512, 4) void scores_kernel(
    const float* __restrict__ pa, const float* __restrict__ pb,
    const float* __restrict__ ca2, const float* __restrict__ cb2,
    const float* __restrict__ W2,
    __hip_bfloat16* __restrict__ Spart, __hip_bfloat16* __restrict__ SpartT)
{
    __shared__ float spa[NCH][64][36];   // 18.4 KB
    __shared__ float sS[64][65];         // 16.6 KB transpose buffer

    const int t  = threadIdx.x;
    const int i0 = (blockIdx.x & 1) * 64;
    const int j0 = (blockIdx.x >> 1) * 64;
    const int nc = blockIdx.y;           // 0..127

    for (int f = t; f < NCH * 64 * 8; f += 512) {
        int h4 = f & 7, row = (f >> 3) & 63, nn = f >> 9;
        *(float4*)&spa[nn][row][h4 * 4] =
            *(const float4*)&pa[((nc * NCH + nn) * D + i0 + row) * HD + h4 * 4];
    }

    float w2r[HD];                        // uniform -> SGPRs
    #pragma unroll
    for (int hh = 0; hh < HD; ++hh) w2r[hh] = 0.5f * W2[hh];

    __syncthreads();

    const int lane = t & 63;
    const int jb   = __builtin_amdgcn_readfirstlane((t >> 6) * 8);

    float accA[8], accB[8];
    #pragma unroll
    for (int jj = 0; jj < 8; ++jj) { accA[jj] = 0.f; accB[jj] = 0.f; }

    #pragma unroll 1
    for (int nn = 0; nn < NCH; ++nn) {
        const int n = nc * NCH + nn;
        float par[HD];                    // this lane's pa row
        #pragma unroll
        for (int k = 0; k < 8; ++k)
            *(float4*)&par[k * 4] = *(const float4*)&spa[nn][lane][k * 4];
        const float cai = ca2[n * D + i0 + lane];
        const float* __restrict__ pbn  = pb  + (size_t)(n * D + j0) * HD;
        const float* __restrict__ cb2n = cb2 + (size_t)n * D + j0;
        #pragma unroll 4
        for (int jj = 0; jj < 8; ++jj) {
            const int j = jb + jj;        // wave-uniform
            const float* pbrow = pbn + j * HD;
            float a = accA[jj] + (cai + cb2n[j]);
            float b = accB[jj];
            #pragma unroll
            for (int k = 0; k < 4; ++k) {
                float4 v = *(const float4*)&pbrow[k * 4];
                a = fmaf(w2r[k*4+0], fabsf(par[k*4+0] + v.x), a);
                a = fmaf(w2r[k*4+1], fabsf(par[k*4+1] + v.y), a);
                a = fmaf(w2r[k*4+2], fabsf(par[k*4+2] + v.z), a);
                a = fmaf(w2r[k*4+3], fabsf(par[k*4+3] + v.w), a);
            }
            #pragma unroll
            for (int k = 4; k < 8; ++k) {
                float4 v = *(const float4*)&pbrow[k * 4];
                b = fmaf(w2r[k*4+0], fabsf(par[k*4+0] + v.x), b);
                b = fmaf(w2r[k*4+1], fabsf(par[k*4+1] + v.y), b);
                b = fmaf(w2r[k*4+2], fabsf(par[k*4+2] + v.z), b);
                b = fmaf(w2r[k*4+3], fabsf(par[k*4+3] + v.w), b);
            }
            accA[jj] = a; accB[jj] = b;
        }
    }

    // ---- epilogue: bf16 partials, both orientations, coalesced ----
    {   // SpartT[nc][j][i]; lanes = consecutive i
        __hip_bfloat16* SpT = SpartT + ((size_t)nc * D + j0 + jb) * D + i0;
        #pragma unroll
        for (int jj = 0; jj < 8; ++jj)
            SpT[jj * D + lane] = __float2bfloat16(accA[jj] + accB[jj]);
    }
    #pragma unroll
    for (int jj = 0; jj < 8; ++jj)
        sS[lane][jb + jj] = accA[jj] + accB[jj];
    __syncthreads();
    {   // Spart[nc][i][j] via LDS transpose, 16B stores
        int ir = t >> 3;
        int jc = (t & 7) * 8;
        unsigned int pk[4];
        #pragma unroll
        for (int k = 0; k < 4; ++k) {
            unsigned int lo = f2bf(sS[ir][jc + 2 * k]);
            unsigned int hi = f2bf(sS[ir][jc + 2 * k + 1]);
            pk[k] = (hi << 16) | lo;
        }
        __hip_bfloat16* Sp = Spart + ((size_t)nc * D + i0 + ir) * D + j0 + jc;
        *(uint4*)Sp = *(uint4*)pk;
    }
}

// ---------------------------------------------------------------------------
// K3: reduce 128 bf16 chunk-partials (4-way split + wave shuffle), antisym,
// sigmoids, Wm. b2 cancels exactly in S - S^T. 256 blocks = full chip.
// ---------------------------------------------------------------------------
__global__ __launch_bounds__(256) void finalize_kernel(
    const __hip_bfloat16* __restrict__ Spart,
    const __hip_bfloat16* __restrict__ SpartT,
    const float* __restrict__ Wmag, float* __restrict__ out)
{
    const int t    = threadIdx.x;
    const int lane = t & 63;
    const int o    = lane & 15;               // output within 16
    const int g    = lane >> 4;               // chunk group 0..3
    const int wv   = t >> 6;                  // wave 0..3
    const int idx  = blockIdx.x * 64 + wv * 16 + o;   // 0..16383

    float s = 0.f;
    #pragma unroll 8
    for (int q = 0; q < 32; ++q) {
        int c = g * 32 + q;
        s += __bfloat162float(Spart [(size_t)c * D * D + idx])
           - __bfloat162float(SpartT[(size_t)c * D * D + idx]);
    }
    s += __shfl_xor(s, 16);
    s += __shfl_xor(s, 32);

    if (g == 0) {
        const int i = idx >> 7, j = idx & 127;
        float av  = s * (1.0f / 256.0f);      // mean over n; TAU=1, b2 cancels
        float dir = 1.0f / (1.0f + __expf(-av));
        float wm  = 0.5f * (Wmag[i * D + j] + Wmag[j * D + i]);
        float A;
        if (i == j) { wm = 0.f; A = 0.f; }
        else        { A = dir / (1.0f + __expf(-wm)); }
        out[idx]         = A;
        out[D * D + idx] = wm;
    }
}

extern "C" void kernel_launch(void* const* d_in, const int* in_sizes, int n_in,
                              void* d_out, int out_size, void* d_ws, size_t ws_size,
                              hipStream_t stream)
{
    const float* z    = (const float*)d_in[0];   // (4,64,128,32)
    const float* Wmag = (const float*)d_in[1];   // (128,128)
    const float* W1   = (const float*)d_in[2];   // (32,64)
    const float* b1   = (const float*)d_in[3];   // (32,)
    const float* W2   = (const float*)d_in[4];   // (1,32)
    // d_in[5] = b2: cancels in scores - scores^T.

    float* pa   = (float*)d_ws;                          // 4 MB
    float* pb   = pa + (size_t)NROWS * HD;               // 4 MB
    float* ca2  = pb + (size_t)NROWS * HD;               // 128 KB
    float* cb2  = ca2 + NROWS;                           // 128 KB
    __hip_bfloat16* Spart  = (__hip_bfloat16*)(cb2 + NROWS);     // 4 MB
    __hip_bfloat16* SpartT = Spart + (size_t)NC * D * D;         // 4 MB
    float* out = (float*)d_out;

    pab_kernel<<<NROWS / 128, 512, 0, stream>>>(z, W1, b1, W2, pa, pb, ca2, cb2);
    scores_kernel<<<dim3(4, NC), 512, 0, stream>>>(pa, pb, ca2, cb2, W2, Spart, SpartT);
    finalize_kernel<<<(D * D) / 64, 256, 0, stream>>>(Spart, SpartT, Wmag, out);
}

// Round 7
// 46.177 us; speedup vs baseline: 2.1247x; 2.1247x over previous
//
#include <hip/hip_runtime.h>
#include <hip/hip_bf16.h>
#include <math.h>

#define D    128
#define NT   256             // B*T
#define HD   32
#define LD   32
#define PADW 132             // 128 + 4 pad: row h starts at bank 4h%32

static __device__ inline unsigned short f2bf(float f) {
    __hip_bfloat16 b = __float2bfloat16(f);
    return *reinterpret_cast<unsigned short*>(&b);
}
static __device__ inline float bf2f(unsigned short u) {
    union { unsigned int i; float f; } v;
    v.i = ((unsigned int)u) << 16;
    return v.f;
}

// ---------------------------------------------------------------------------
// K12: one block per token n (grid 256, 512 thr).
//  phase 1: pa'[h][i] = b1[h] + z[i]·W1a[h], pb[h][i] = z[i]·W1b[h]
//           -> straight into LDS, h-major (no global roundtrip).
//           W1 in VGPRs (2 h-rows/thread), z staged once in LDS,
//           all LDS reads lane-distinct b128.
//  phase 2: rank-1 relu-split terms via LDS column sums.
//  phase 3: S[i][j] = lin + sum_h (w2[h]/2)|pa'+pb|, thread tile 4i x 8j:
//           per h: 3 lane-distinct b128 reads + 64 VALU (add + fma|.|).
//  epilogue: bf16 per-n partials, both orientations, from registers.
// ---------------------------------------------------------------------------
__global__ __launch_bounds__(512) void fused_pab_scores(
    const float* __restrict__ z, const float* __restrict__ W1,
    const float* __restrict__ b1, const float* __restrict__ W2,
    __hip_bfloat16* __restrict__ Sp, __hip_bfloat16* __restrict__ SpT)
{
    __shared__ float sz[D * LD];        // 16 KB
    __shared__ float spa[HD][PADW];     // 16.9 KB
    __shared__ float spb[HD][PADW];     // 16.9 KB
    __shared__ float sLin[2][4][D];     // 4 KB

    const int t = threadIdx.x;
    const int n = blockIdx.x;

    // ---- stage z slab (16 KB, coalesced) ----
    {
        const float4* zsrc = (const float4*)(z + (size_t)n * (D * LD));
        float4* zdst = (float4*)sz;
        zdst[t]       = zsrc[t];
        zdst[t + 512] = zsrc[t + 512];
    }

    // ---- W1 rows into VGPRs: thread owns h0=2*hh, h1=h0+1, i-quad iq ----
    const int iq = t & 31;
    const int hh = t >> 5;              // 0..15
    const int h0 = 2 * hh, h1 = h0 + 1;
    float wa0[LD], wa1[LD], wb0[LD], wb1[LD];
    #pragma unroll
    for (int k = 0; k < 8; ++k) {
        *(float4*)&wa0[k*4] = *(const float4*)&W1[h0 * 64 + k*4];
        *(float4*)&wb0[k*4] = *(const float4*)&W1[h0 * 64 + 32 + k*4];
        *(float4*)&wa1[k*4] = *(const float4*)&W1[h1 * 64 + k*4];
        *(float4*)&wb1[k*4] = *(const float4*)&W1[h1 * 64 + 32 + k*4];
    }
    const float bias0 = b1[h0], bias1 = b1[h1];
    __syncthreads();

    // ---- phase 1: 4 i's x 2 h's per thread -> spa/spb (h-major) ----
    {
        float ra0[4], ra1[4], rb0[4], rb1[4];
        #pragma unroll
        for (int r = 0; r < 4; ++r) {
            const int i = iq * 4 + r;
            float zr[LD];
            #pragma unroll
            for (int k = 0; k < 8; ++k)
                *(float4*)&zr[k*4] = *(const float4*)&sz[i * LD + k*4];
            float a0 = bias0, a1 = bias1, c0 = 0.f, c1 = 0.f;
            #pragma unroll
            for (int l = 0; l < LD; ++l) {
                a0 = fmaf(zr[l], wa0[l], a0);
                a1 = fmaf(zr[l], wa1[l], a1);
                c0 = fmaf(zr[l], wb0[l], c0);
                c1 = fmaf(zr[l], wb1[l], c1);
            }
            ra0[r] = a0; ra1[r] = a1; rb0[r] = c0; rb1[r] = c1;
        }
        *(float4*)&spa[h0][iq * 4] = *(float4*)ra0;
        *(float4*)&spa[h1][iq * 4] = *(float4*)ra1;
        *(float4*)&spb[h0][iq * 4] = *(float4*)rb0;
        *(float4*)&spb[h1][iq * 4] = *(float4*)rb1;
    }

    float w2r[HD];                      // uniform -> SGPRs
    #pragma unroll
    for (int h = 0; h < HD; ++h) w2r[h] = 0.5f * W2[h];
    __syncthreads();

    // ---- phase 2: rank-1 linear terms (relu(x) = (x+|x|)/2 split) ----
    {
        const int i = t & 127, g = t >> 7;      // g 0..3: 8 h's each
        float sa = 0.f, sb = 0.f;
        #pragma unroll
        for (int q = 0; q < 8; ++q) {
            int h = g * 8 + q;
            sa = fmaf(w2r[h], spa[h][i], sa);
            sb = fmaf(w2r[h], spb[h][i], sb);
        }
        sLin[0][g][i] = sa;
        sLin[1][g][i] = sb;
    }
    __syncthreads();

    // ---- phase 3: abs part, 4i x 8j per thread ----
    const int tx = t & 15;              // j-oct
    const int ty = t >> 4;              // i-quad 0..31
    float acc[4][8];
    #pragma unroll
    for (int r = 0; r < 4; ++r)
        #pragma unroll
        for (int c = 0; c < 8; ++c) acc[r][c] = 0.f;

    #pragma unroll 4
    for (int h = 0; h < HD; ++h) {
        float4 av = *(const float4*)&spa[h][ty * 4];
        float4 u0 = *(const float4*)&spb[h][tx * 8];
        float4 u4 = *(const float4*)&spb[h][tx * 8 + 4];
        const float w = w2r[h];
        float ar[4] = {av.x, av.y, av.z, av.w};
        float br[8] = {u0.x, u0.y, u0.z, u0.w, u4.x, u4.y, u4.z, u4.w};
        #pragma unroll
        for (int r = 0; r < 4; ++r)
            #pragma unroll
            for (int c = 0; c < 8; ++c)
                acc[r][c] = fmaf(w, fabsf(ar[r] + br[c]), acc[r][c]);
    }

    // ---- add linear terms ----
    float cai[4], cbj[8];
    #pragma unroll
    for (int r = 0; r < 4; ++r) {
        int i = ty * 4 + r;
        cai[r] = sLin[0][0][i] + sLin[0][1][i] + sLin[0][2][i] + sLin[0][3][i];
    }
    #pragma unroll
    for (int c = 0; c < 8; ++c) {
        int j = tx * 8 + c;
        cbj[c] = sLin[1][0][j] + sLin[1][1][j] + sLin[1][2][j] + sLin[1][3][j];
    }
    #pragma unroll
    for (int r = 0; r < 4; ++r)
        #pragma unroll
        for (int c = 0; c < 8; ++c)
            acc[r][c] += cai[r] + cbj[c];

    // ---- epilogue: bf16 partials, both orientations, from registers ----
    __hip_bfloat16* Spn  = Sp  + (size_t)n * (D * D);
    __hip_bfloat16* SpTn = SpT + (size_t)n * (D * D);
    #pragma unroll
    for (int r = 0; r < 4; ++r) {       // Sp[n][i][j], coalesced uint4
        unsigned int pk[4];
        #pragma unroll
        for (int k = 0; k < 4; ++k)
            pk[k] = ((unsigned int)f2bf(acc[r][2*k+1]) << 16) | f2bf(acc[r][2*k]);
        *(uint4*)&Spn[(ty * 4 + r) * D + tx * 8] = *(uint4*)pk;
    }
    #pragma unroll
    for (int c = 0; c < 8; ++c) {       // SpT[n][j][i], uint2 per j-row
        unsigned int pk[2];
        pk[0] = ((unsigned int)f2bf(acc[1][c]) << 16) | f2bf(acc[0][c]);
        pk[1] = ((unsigned int)f2bf(acc[3][c]) << 16) | f2bf(acc[2][c]);
        *(uint2*)&SpTn[(tx * 8 + c) * D + ty * 4] = *(uint2*)pk;
    }
}

// ---------------------------------------------------------------------------
// K3: out-row per block (grid 128, 512 thr). Sum 256 per-n bf16 partials
// (both orientations row-coalesced uint4), LDS tree over 32 n-groups,
// then antisym/sigmoid/Wm finalize. b2 cancels in S - S^T.
// ---------------------------------------------------------------------------
__global__ __launch_bounds__(512) void finalize_kernel(
    const __hip_bfloat16* __restrict__ Sp,
    const __hip_bfloat16* __restrict__ SpT,
    const float* __restrict__ Wmag, float* __restrict__ out)
{
    __shared__ float sG[32][136];       // 17.4 KB; 136: 16B-aligned rows

    const int t   = threadIdx.x;
    const int row = blockIdx.x;         // i = row
    const int jo  = t & 15;             // j-oct
    const int g   = t >> 4;             // n-group 0..31 (8 n's each)

    float a8[8];
    #pragma unroll
    for (int k = 0; k < 8; ++k) a8[k] = 0.f;

    #pragma unroll 2
    for (int q = 0; q < 8; ++q) {
        const size_t off = (size_t)(g * 8 + q) * (D * D) + row * D + jo * 8;
        uint4 sp = *(const uint4*)&Sp[off];
        uint4 st = *(const uint4*)&SpT[off];
        unsigned int xs[4] = {sp.x, sp.y, sp.z, sp.w};
        unsigned int ys[4] = {st.x, st.y, st.z, st.w};
        #pragma unroll
        for (int k = 0; k < 4; ++k) {
            a8[2*k]   += bf2f((unsigned short)(xs[k] & 0xffff))
                       - bf2f((unsigned short)(ys[k] & 0xffff));
            a8[2*k+1] += bf2f((unsigned short)(xs[k] >> 16))
                       - bf2f((unsigned short)(ys[k] >> 16));
        }
    }
    *(float4*)&sG[g][jo * 8]     = make_float4(a8[0], a8[1], a8[2], a8[3]);
    *(float4*)&sG[g][jo * 8 + 4] = make_float4(a8[4], a8[5], a8[6], a8[7]);
    __syncthreads();

    if (t < D) {
        const int j = t;
        float s = 0.f;
        #pragma unroll 8
        for (int gg = 0; gg < 32; ++gg) s += sG[gg][j];

        float av  = s * (1.0f / 256.0f);        // mean over n; TAU = 1
        float dir = 1.0f / (1.0f + __expf(-av));
        float wm  = 0.5f * (Wmag[row * D + j] + Wmag[j * D + row]);
        float A;
        if (row == j) { wm = 0.f; A = 0.f; }
        else          { A = dir / (1.0f + __expf(-wm)); }
        out[row * D + j]         = A;
        out[D * D + row * D + j] = wm;
    }
}

extern "C" void kernel_launch(void* const* d_in, const int* in_sizes, int n_in,
                              void* d_out, int out_size, void* d_ws, size_t ws_size,
                              hipStream_t stream)
{
    const float* z    = (const float*)d_in[0];   // (4,64,128,32)
    const float* Wmag = (const float*)d_in[1];   // (128,128)
    const float* W1   = (const float*)d_in[2];   // (32,64)
    const float* b1   = (const float*)d_in[3];   // (32,)
    const float* W2   = (const float*)d_in[4];   // (1,32)
    // d_in[5] = b2: cancels in scores - scores^T.

    __hip_bfloat16* Sp  = (__hip_bfloat16*)d_ws;              // 256*16384 bf16 = 8 MB
    __hip_bfloat16* SpT = Sp + (size_t)NT * D * D;            // 8 MB
    float* out = (float*)d_out;

    fused_pab_scores<<<NT, 512, 0, stream>>>(z, W1, b1, W2, Sp, SpT);
    finalize_kernel<<<D, 512, 0, stream>>>(Sp, SpT, Wmag, out);
}

// Round 8
// 33.027 us; speedup vs baseline: 2.9707x; 1.3982x over previous
//
#include <hip/hip_runtime.h>
#include <hip/hip_bf16.h>
#include <math.h>

#define D    128
#define NT   256             // B*T
#define HD   32
#define LD   32
#define PADW 132             // spa/spb row pad (floats)

static __device__ inline unsigned short f2bf(float f) {
    __hip_bfloat16 b = __float2bfloat16(f);
    return *reinterpret_cast<unsigned short*>(&b);
}
static __device__ inline float bf2f(unsigned short u) {
    union { unsigned int i; float f; } v;
    v.i = ((unsigned int)u) << 16;
    return v.f;
}

union SmemA {                       // z (phase 1) overlaid with sLin (phase 2+)
    float zt[LD][PADW];             // z transposed: zt[l][i], 16.9 KB
    float lin[2][4][D];             // rank-1 relu-split terms, 4 KB
};
union SmemB {                       // pa/pb tiles overlaid with transpose buf
    struct { float spa[HD][PADW]; float spb[HD][PADW]; } p;   // 33.8 KB
    unsigned short st[D][PADW];                               // bf16 S, 33.8 KB
};

// ---------------------------------------------------------------------------
// K12: one block per token n (grid 256, 512 thr).
//  P1: pa'[h][i], pb[h][i] from z (W1 in VGPRs; zt read as 4-way-clean b128).
//  P2: rank-1 linear terms of relu-split.
//  P3: S[i][j] = lin + sum_h (w2[h]/2)|pa'+pb|, thread tile 4i x 8j.
//  epilogue: S -> LDS bf16 transpose buffer -> write ONLY D = S - S^T (bf16).
// ---------------------------------------------------------------------------
__global__ __launch_bounds__(512) void fused_pab_scores(
    const float* __restrict__ z, const float* __restrict__ W1,
    const float* __restrict__ b1, const float* __restrict__ W2,
    unsigned short* __restrict__ Dp)        // bf16 D[n][i][j], 8 MB
{
    __shared__ SmemA sa;
    __shared__ SmemB sb;

    const int t = threadIdx.x;
    const int n = blockIdx.x;

    // ---- stage z TRANSPOSED: zt[l][i] (coalesced read, 4-way write) ----
    {
        const float4* zsrc = (const float4*)(z + (size_t)n * (D * LD));
        #pragma unroll
        for (int q = 0; q < 2; ++q) {
            int f = t + q * 512;            // 1024 float4 total
            float4 v = zsrc[f];
            int flat = f * 4;
            int i = flat >> 5, l = flat & 31;
            sa.zt[l + 0][i] = v.x; sa.zt[l + 1][i] = v.y;
            sa.zt[l + 2][i] = v.z; sa.zt[l + 3][i] = v.w;
        }
    }

    // ---- W1 rows into VGPRs; w2/b1 (overlap staging latency) ----
    const int iq = t & 31;                  // i-quad for P1
    const int hh = t >> 5;                  // 0..15
    const int h0 = 2 * hh, h1 = h0 + 1;
    float wa0[LD], wa1[LD], wb0[LD], wb1[LD];
    #pragma unroll
    for (int k = 0; k < 8; ++k) {
        *(float4*)&wa0[k*4] = *(const float4*)&W1[h0 * 64 + k*4];
        *(float4*)&wb0[k*4] = *(const float4*)&W1[h0 * 64 + 32 + k*4];
        *(float4*)&wa1[k*4] = *(const float4*)&W1[h1 * 64 + k*4];
        *(float4*)&wb1[k*4] = *(const float4*)&W1[h1 * 64 + 32 + k*4];
    }
    const float bias0 = b1[h0], bias1 = b1[h1];
    float w2r[HD];                          // uniform -> SGPRs
    #pragma unroll
    for (int h = 0; h < HD; ++h) w2r[h] = 0.5f * W2[h];
    __syncthreads();

    // ---- P1: 4 i's x 2 h's per thread; 16 indep fma chains ----
    {
        float a0[4], a1[4], c0[4], c1[4];
        #pragma unroll
        for (int r = 0; r < 4; ++r) { a0[r] = bias0; a1[r] = bias1; c0[r] = 0.f; c1[r] = 0.f; }
        #pragma unroll
        for (int l = 0; l < LD; ++l) {
            float4 zv = *(const float4*)&sa.zt[l][iq * 4];
            float zr[4] = {zv.x, zv.y, zv.z, zv.w};
            #pragma unroll
            for (int r = 0; r < 4; ++r) {
                a0[r] = fmaf(zr[r], wa0[l], a0[r]);
                a1[r] = fmaf(zr[r], wa1[l], a1[r]);
                c0[r] = fmaf(zr[r], wb0[l], c0[r]);
                c1[r] = fmaf(zr[r], wb1[l], c1[r]);
            }
        }
        *(float4*)&sb.p.spa[h0][iq*4] = make_float4(a0[0], a0[1], a0[2], a0[3]);
        *(float4*)&sb.p.spa[h1][iq*4] = make_float4(a1[0], a1[1], a1[2], a1[3]);
        *(float4*)&sb.p.spb[h0][iq*4] = make_float4(c0[0], c0[1], c0[2], c0[3]);
        *(float4*)&sb.p.spb[h1][iq*4] = make_float4(c1[0], c1[1], c1[2], c1[3]);
    }
    __syncthreads();                        // spa/spb ready; zt dead

    // ---- P2: rank-1 linear terms (relu(x) = x/2 + |x|/2) ----
    {
        const int i2 = t & 127, g2 = t >> 7;    // 4 groups x 8 h
        float sA = 0.f, sB = 0.f;
        #pragma unroll
        for (int q = 0; q < 8; ++q) {
            int h = g2 * 8 + q;
            sA = fmaf(w2r[h], sb.p.spa[h][i2], sA);
            sB = fmaf(w2r[h], sb.p.spb[h][i2], sB);
        }
        sa.lin[0][g2][i2] = sA;
        sa.lin[1][g2][i2] = sB;
    }
    __syncthreads();

    // ---- P3: abs part, 4i x 8j per thread ----
    const int tx = t & 15;                  // j-oct
    const int ty = t >> 4;                  // i-quad 0..31
    float acc[4][8];
    #pragma unroll
    for (int r = 0; r < 4; ++r)
        #pragma unroll
        for (int c = 0; c < 8; ++c) acc[r][c] = 0.f;

    #pragma unroll 4
    for (int h = 0; h < HD; ++h) {
        float4 av = *(const float4*)&sb.p.spa[h][ty * 4];
        float4 u0 = *(const float4*)&sb.p.spb[h][tx * 8];
        float4 u4 = *(const float4*)&sb.p.spb[h][tx * 8 + 4];
        const float w = w2r[h];
        float ar[4] = {av.x, av.y, av.z, av.w};
        float br[8] = {u0.x, u0.y, u0.z, u0.w, u4.x, u4.y, u4.z, u4.w};
        #pragma unroll
        for (int r = 0; r < 4; ++r)
            #pragma unroll
            for (int c = 0; c < 8; ++c)
                acc[r][c] = fmaf(w, fabsf(ar[r] + br[c]), acc[r][c]);
    }

    // ---- add linear terms: S complete ----
    {
        float cai[4], cbj[8];
        #pragma unroll
        for (int r = 0; r < 4; ++r) {
            int i = ty * 4 + r;
            cai[r] = sa.lin[0][0][i] + sa.lin[0][1][i] + sa.lin[0][2][i] + sa.lin[0][3][i];
        }
        #pragma unroll
        for (int c = 0; c < 8; ++c) {
            int j = tx * 8 + c;
            cbj[c] = sa.lin[1][0][j] + sa.lin[1][1][j] + sa.lin[1][2][j] + sa.lin[1][3][j];
        }
        #pragma unroll
        for (int r = 0; r < 4; ++r)
            #pragma unroll
            for (int c = 0; c < 8; ++c)
                acc[r][c] += cai[r] + cbj[c];
    }
    __syncthreads();                        // spa/spb dead -> overlay st

    // ---- epilogue: S -> LDS bf16, in-block transpose, write D only ----
    #pragma unroll
    for (int r = 0; r < 4; ++r) {           // write S rows (b64, 2-way clean)
        int i = ty * 4 + r;
        unsigned int pk[4];
        #pragma unroll
        for (int k = 0; k < 4; ++k)
            pk[k] = ((unsigned int)f2bf(acc[r][2*k+1]) << 16) | f2bf(acc[r][2*k]);
        *(uint2*)&sb.st[i][tx * 8]     = make_uint2(pk[0], pk[1]);
        *(uint2*)&sb.st[i][tx * 8 + 4] = make_uint2(pk[2], pk[3]);
    }
    __syncthreads();

    unsigned short* Dn = Dp + (size_t)n * (D * D);
    float dre[4][8];
    #pragma unroll
    for (int c = 0; c < 8; ++c) {           // transposed reads (b64, ~8-way)
        int j = tx * 8 + c;
        uint2 tv = *(const uint2*)&sb.st[j][ty * 4];   // S[j][ty*4..+3]
        dre[0][c] = acc[0][c] - bf2f((unsigned short)(tv.x & 0xffff));
        dre[1][c] = acc[1][c] - bf2f((unsigned short)(tv.x >> 16));
        dre[2][c] = acc[2][c] - bf2f((unsigned short)(tv.y & 0xffff));
        dre[3][c] = acc[3][c] - bf2f((unsigned short)(tv.y >> 16));
    }
    #pragma unroll
    for (int r = 0; r < 4; ++r) {           // D[n][i][j], coalesced uint4
        unsigned int pk[4];
        #pragma unroll
        for (int k = 0; k < 4; ++k)
            pk[k] = ((unsigned int)f2bf(dre[r][2*k+1]) << 16) | f2bf(dre[r][2*k]);
        *(uint4*)&Dn[(ty * 4 + r) * D + tx * 8] = *(uint4*)pk;
    }
}

// ---------------------------------------------------------------------------
// K3: mean over n of D (8 MB read, fully coalesced, no transposed access),
// sigmoid / Wm finalize. b2 cancelled; D already antisymmetric.
// grid 256 x 256 thr; block b owns 64 output cells (half an i-row).
// ---------------------------------------------------------------------------
__global__ __launch_bounds__(256) void finalize_kernel(
    const unsigned short* __restrict__ Dp, const float* __restrict__ Wmag,
    float* __restrict__ out)
{
    __shared__ float red[8][68];

    const int t = threadIdx.x, b = blockIdx.x;
    const int c2 = (t & 31) * 2;            // cell pair within block's 64
    const int g  = t >> 5;                  // n-group 0..7 (32 n's each)
    const int base = b * 64;

    float s0 = 0.f, s1 = 0.f;
    #pragma unroll 8
    for (int q = 0; q < 32; ++q) {
        int nn = g * 32 + q;
        unsigned int u = *(const unsigned int*)&Dp[(size_t)nn * (D * D) + base + c2];
        s0 += bf2f((unsigned short)(u & 0xffff));
        s1 += bf2f((unsigned short)(u >> 16));
    }
    red[g][c2]     = s0;
    red[g][c2 + 1] = s1;
    __syncthreads();

    if (t < 64) {
        float s = 0.f;
        #pragma unroll
        for (int gg = 0; gg < 8; ++gg) s += red[gg][t];
        const int idx = base + t;
        const int i = idx >> 7, j = idx & 127;
        float av  = s * (1.0f / 256.0f);    // mean over n; TAU = 1
        float dir = 1.0f / (1.0f + __expf(-av));
        float wm  = 0.5f * (Wmag[i * D + j] + Wmag[j * D + i]);
        float A;
        if (i == j) { wm = 0.f; A = 0.f; }
        else        { A = dir / (1.0f + __expf(-wm)); }
        out[idx]         = A;
        out[D * D + idx] = wm;
    }
}

extern "C" void kernel_launch(void* const* d_in, const int* in_sizes, int n_in,
                              void* d_out, int out_size, void* d_ws, size_t ws_size,
                              hipStream_t stream)
{
    const float* z    = (const float*)d_in[0];   // (4,64,128,32)
    const float* Wmag = (const float*)d_in[1];   // (128,128)
    const float* W1   = (const float*)d_in[2];   // (32,64)
    const float* b1   = (const float*)d_in[3];   // (32,)
    const float* W2   = (const float*)d_in[4];   // (1,32)
    // d_in[5] = b2: cancels in scores - scores^T.

    unsigned short* Dp = (unsigned short*)d_ws;  // bf16 D[n][i][j], 8 MB
    float* out = (float*)d_out;

    fused_pab_scores<<<NT, 512, 0, stream>>>(z, W1, b1, W2, Dp);
    finalize_kernel<<<NT, 256, 0, stream>>>(Dp, Wmag, out);
}